// Round 1
// baseline (4540.493 us; speedup 1.0000x reference)
//
#include <hip/hip_runtime.h>

#define NN 100000      // nodes
#define NE 1600000     // edges
#define INC 128        // in channels
#define HID 96         // hidden
#define NG 512         // graphs

// ---------------- degree / norm ----------------
__global__ void k_init_deg(float* deg) {
    int i = blockIdx.x * blockDim.x + threadIdx.x;
    if (i < NN) deg[i] = 1.0f;   // self loop
}

__global__ void k_deg_edges(const int* __restrict__ dst, float* deg) {
    int e = blockIdx.x * blockDim.x + threadIdx.x;
    if (e < NE) atomicAdd(&deg[dst[e]], 1.0f);
}

__global__ void k_dis(float* deg) {
    int i = blockIdx.x * blockDim.x + threadIdx.x;
    if (i < NN) deg[i] = rsqrtf(deg[i]);   // deg >= 1 always
}

__global__ void k_norm(const int* __restrict__ src, const int* __restrict__ dst,
                       const float* __restrict__ dis, float* __restrict__ norm) {
    int e = blockIdx.x * blockDim.x + threadIdx.x;
    if (e < NE) norm[e] = dis[src[e]] * dis[dst[e]];
}

// ---------------- dense GEMM: Y[N,HID] = X[N,K] @ W[K,HID] ----------------
template <int K>
__global__ __launch_bounds__(256) void k_gemm(const float* __restrict__ X,
                                              const float* __restrict__ W,
                                              float* __restrict__ Y, int nrows) {
    __shared__ float xs[32][K];
    const int tid = threadIdx.x;
    const int row0 = blockIdx.x * 32;
    // stage 32 rows of X into LDS (float4)
    for (int idx = tid * 4; idx < 32 * K; idx += 256 * 4) {
        int r = idx / K, c = idx % K;
        int grow = row0 + r;
        float4 v = make_float4(0.f, 0.f, 0.f, 0.f);
        if (grow < nrows) v = *(const float4*)&X[(size_t)grow * K + c];
        *(float4*)&xs[r][c] = v;
    }
    __syncthreads();
    for (int idx = tid; idx < 32 * HID; idx += 256) {
        int r = idx / HID, c = idx % HID;
        int grow = row0 + r;
        if (grow >= nrows) continue;
        float acc = 0.f;
#pragma unroll 8
        for (int k = 0; k < K; ++k) acc += xs[r][k] * W[k * HID + c];
        Y[(size_t)grow * HID + c] = acc;
    }
}

// ---------------- scatter: B init with self-loop term ----------------
__global__ void k_selfloop(const float* __restrict__ A, const float* __restrict__ dis,
                           float* __restrict__ B) {
    int i = blockIdx.x * blockDim.x + threadIdx.x;
    if (i < NN * HID) {
        int node = i / HID;
        float d = dis[node];
        B[i] = A[i] * d * d;
    }
}

// 24 threads per edge, float4 each (96 feats)
__global__ void k_scatter(const int* __restrict__ src, const int* __restrict__ dst,
                          const float* __restrict__ norm, const float* __restrict__ A,
                          float* __restrict__ B) {
    int gid = blockIdx.x * blockDim.x + threadIdx.x;
    int e = gid / 24;
    int r = gid % 24;
    if (e >= NE) return;
    int s = src[e], d = dst[e];
    float w = norm[e];
    float4 v = *(const float4*)&A[(size_t)s * HID + r * 4];
    float* bp = &B[(size_t)d * HID + r * 4];
    atomicAdd(bp + 0, v.x * w);
    atomicAdd(bp + 1, v.y * w);
    atomicAdd(bp + 2, v.z * w);
    atomicAdd(bp + 3, v.w * w);
}

__global__ void k_bias_relu(const float* __restrict__ B, const float* __restrict__ bias,
                            float* __restrict__ C) {
    int i = blockIdx.x * blockDim.x + threadIdx.x;
    if (i < NN * HID) {
        int f = i % HID;
        C[i] = fmaxf(B[i] + bias[f], 0.f);
    }
}

// ---------------- node head ----------------
__global__ void k_node_logits(const float* __restrict__ h1, const float* __restrict__ h2,
                              const float* __restrict__ Wn, const float* __restrict__ bn,
                              float* __restrict__ out) {
    int i = blockIdx.x * blockDim.x + threadIdx.x;
    if (i >= NN) return;
    float acc = bn[0];
    const float4* a = (const float4*)&h1[(size_t)i * HID];
    const float4* b = (const float4*)&h2[(size_t)i * HID];
#pragma unroll
    for (int k = 0; k < 24; ++k) {
        float4 v = a[k];
        acc += v.x * Wn[k * 4 + 0] + v.y * Wn[k * 4 + 1] + v.z * Wn[k * 4 + 2] + v.w * Wn[k * 4 + 3];
    }
#pragma unroll
    for (int k = 0; k < 24; ++k) {
        float4 v = b[k];
        acc += v.x * Wn[96 + k * 4 + 0] + v.y * Wn[96 + k * 4 + 1] + v.z * Wn[96 + k * 4 + 2] +
               v.w * Wn[96 + k * 4 + 3];
    }
    out[i] = acc;
}

// ---------------- graph pooling + graph head ----------------
__global__ __launch_bounds__(192) void k_pool(const float* __restrict__ h1,
                                              const float* __restrict__ h2,
                                              const int* __restrict__ batch,
                                              const float* __restrict__ Wg,
                                              const float* __restrict__ bg,
                                              float* __restrict__ out) {
    int g = blockIdx.x;
    int tid = threadIdx.x;  // 0..191
    // lower_bound(batch, g) and lower_bound(batch, g+1) — batch is sorted
    int lo = 0, hi = NN;
    while (lo < hi) { int mid = (lo + hi) >> 1; if (batch[mid] < g) lo = mid + 1; else hi = mid; }
    int start = lo;
    hi = NN;
    while (lo < hi) { int mid = (lo + hi) >> 1; if (batch[mid] < g + 1) lo = mid + 1; else hi = mid; }
    int end = lo;

    const float* hsrc = (tid < HID) ? h1 : h2;
    int f = (tid < HID) ? tid : tid - HID;
    float sum = 0.f, mx = 0.f;  // h >= 0 post-relu, so 0-init max == segment_max (and handles empty)
    for (int n = start; n < end; ++n) {
        float v = hsrc[(size_t)n * HID + f];
        sum += v;
        mx = fmaxf(mx, v);
    }
    float cnt = (float)(end - start);
    float mean = sum / fmaxf(cnt, 1.0f);
    float contrib = mean * Wg[tid] + mx * Wg[192 + tid];

    __shared__ float red[256];
    red[tid] = contrib;
    if (tid < 64) red[192 + tid] = 0.f;
    __syncthreads();
    for (int s = 128; s > 0; s >>= 1) {
        if (tid < s) red[tid] += red[tid + s];
        __syncthreads();
    }
    if (tid == 0) out[g] = red[0] + bg[0];
}

extern "C" void kernel_launch(void* const* d_in, const int* in_sizes, int n_in,
                              void* d_out, int out_size, void* d_ws, size_t ws_size,
                              hipStream_t stream) {
    const float* x    = (const float*)d_in[0];
    const int*   ei   = (const int*)d_in[1];
    const int*   srcp = ei;
    const int*   dstp = ei + NE;
    const int*   batch = (const int*)d_in[2];
    const float* W1 = (const float*)d_in[3];
    const float* b1 = (const float*)d_in[4];
    const float* W2 = (const float*)d_in[5];
    const float* b2 = (const float*)d_in[6];
    const float* Wn = (const float*)d_in[7];
    const float* bn = (const float*)d_in[8];
    const float* Wg = (const float*)d_in[9];
    const float* bg = (const float*)d_in[10];
    float* out = (float*)d_out;

    float* ws   = (float*)d_ws;
    float* dis  = ws;                          // N
    float* norm = dis + NN;                    // E
    float* A    = norm + NE;                   // N*HID  (hw buffer, later h2)
    float* B    = A + (size_t)NN * HID;        // N*HID  (aggregation)
    float* C    = B + (size_t)NN * HID;        // N*HID  (h1)

    const int TPB = 256;
    // norms
    k_init_deg<<<(NN + TPB - 1) / TPB, TPB, 0, stream>>>(dis);
    k_deg_edges<<<(NE + TPB - 1) / TPB, TPB, 0, stream>>>(dstp, dis);
    k_dis<<<(NN + TPB - 1) / TPB, TPB, 0, stream>>>(dis);
    k_norm<<<(NE + TPB - 1) / TPB, TPB, 0, stream>>>(srcp, dstp, dis, norm);

    const int nElem = NN * HID;
    const int scatterThreads = NE * 24;

    // conv1: A = x@W1 ; B = scatter(A) ; C = relu(B+b1)
    k_gemm<INC><<<(NN + 31) / 32, 256, 0, stream>>>(x, W1, A, NN);
    k_selfloop<<<(nElem + TPB - 1) / TPB, TPB, 0, stream>>>(A, dis, B);
    k_scatter<<<(scatterThreads + TPB - 1) / TPB, TPB, 0, stream>>>(srcp, dstp, norm, A, B);
    k_bias_relu<<<(nElem + TPB - 1) / TPB, TPB, 0, stream>>>(B, b1, C);

    // conv2: A = C@W2 ; B = scatter(A) ; A = relu(B+b2)  (h2 overwrites hw2)
    k_gemm<HID><<<(NN + 31) / 32, 256, 0, stream>>>(C, W2, A, NN);
    k_selfloop<<<(nElem + TPB - 1) / TPB, TPB, 0, stream>>>(A, dis, B);
    k_scatter<<<(scatterThreads + TPB - 1) / TPB, TPB, 0, stream>>>(srcp, dstp, norm, A, B);
    k_bias_relu<<<(nElem + TPB - 1) / TPB, TPB, 0, stream>>>(B, b2, A);

    // heads
    k_node_logits<<<(NN + TPB - 1) / TPB, TPB, 0, stream>>>(C, A, Wn, bn, out + NG);
    k_pool<<<NG, 192, 0, stream>>>(C, A, batch, Wg, bg, out);
}

// Round 2
// 955.214 us; speedup vs baseline: 4.7534x; 4.7534x over previous
//
#include <hip/hip_runtime.h>

#define NN 100000      // nodes
#define NE 1600000     // edges
#define INC 128        // in channels
#define HID 96         // hidden
#define NG 512         // graphs

// ---------------- CSR build: histogram, scan, reorder ----------------
__global__ void k_zero(int* __restrict__ off, int* __restrict__ cur) {
    int i = blockIdx.x * blockDim.x + threadIdx.x;
    if (i < NN + 1) off[i] = 0;
    if (i < NN) cur[i] = 0;
}

__global__ void k_hist(const int* __restrict__ dst, int* __restrict__ off) {
    int e = blockIdx.x * blockDim.x + threadIdx.x;
    if (e < NE) atomicAdd(&off[dst[e] + 1], 1);
}

// single-block inclusive scan over off[0..NN]  (off[0] stays 0)
__global__ __launch_bounds__(1024) void k_scan(int* __restrict__ a, int n) {
    __shared__ int buf[1024];
    __shared__ int carry;
    if (threadIdx.x == 0) carry = 0;
    __syncthreads();
    for (int base = 0; base < n; base += 1024) {
        int i = base + threadIdx.x;
        int v = (i < n) ? a[i] : 0;
        buf[threadIdx.x] = v;
        __syncthreads();
        for (int ofs = 1; ofs < 1024; ofs <<= 1) {
            int t = (threadIdx.x >= ofs) ? buf[threadIdx.x - ofs] : 0;
            __syncthreads();
            buf[threadIdx.x] += t;
            __syncthreads();
        }
        int res = buf[threadIdx.x] + carry;
        if (i < n) a[i] = res;
        __syncthreads();
        if (threadIdx.x == 1023) carry = res;
        __syncthreads();
    }
}

// dis[i] = rsqrt(deg_in + selfloop)
__global__ void k_dis(const int* __restrict__ off, float* __restrict__ dis) {
    int i = blockIdx.x * blockDim.x + threadIdx.x;
    if (i < NN) dis[i] = rsqrtf((float)(off[i + 1] - off[i] + 1));
}

__global__ void k_reorder(const int* __restrict__ src, const int* __restrict__ dst,
                          const int* __restrict__ off, int* __restrict__ cur,
                          int* __restrict__ ssrc) {
    int e = blockIdx.x * blockDim.x + threadIdx.x;
    if (e >= NE) return;
    int d = dst[e];
    int p = off[d] + atomicAdd(&cur[d], 1);
    ssrc[p] = src[e];
}

// ---------------- dense GEMM: Y[N,HID] = X[N,K] @ W[K,HID] ----------------
template <int K>
__global__ __launch_bounds__(256) void k_gemm(const float* __restrict__ X,
                                              const float* __restrict__ W,
                                              float* __restrict__ Y, int nrows) {
    __shared__ float xs[32][K];
    const int tid = threadIdx.x;
    const int row0 = blockIdx.x * 32;
    for (int idx = tid * 4; idx < 32 * K; idx += 256 * 4) {
        int r = idx / K, c = idx % K;
        int grow = row0 + r;
        float4 v = make_float4(0.f, 0.f, 0.f, 0.f);
        if (grow < nrows) v = *(const float4*)&X[(size_t)grow * K + c];
        *(float4*)&xs[r][c] = v;
    }
    __syncthreads();
    for (int idx = tid; idx < 32 * HID; idx += 256) {
        int r = idx / HID, c = idx % HID;
        int grow = row0 + r;
        if (grow >= nrows) continue;
        float acc = 0.f;
#pragma unroll 8
        for (int k = 0; k < K; ++k) acc += xs[r][k] * W[k * HID + c];
        Y[(size_t)grow * HID + c] = acc;
    }
}

// ---------------- fused GCN aggregation: selfloop + segmented sum + bias + relu ----------------
// 32 threads per destination node; thread t owns features {t, t+32, t+64}
__global__ __launch_bounds__(256) void k_agg(const float* __restrict__ A,
                                             const int* __restrict__ ssrc,
                                             const int* __restrict__ off,
                                             const float* __restrict__ dis,
                                             const float* __restrict__ bias,
                                             float* __restrict__ out) {
    int gid = blockIdx.x * blockDim.x + threadIdx.x;
    int d = gid >> 5;
    int t = gid & 31;
    if (d >= NN) return;
    const int beg = off[d], end = off[d + 1];
    const float dd = dis[d];
    const float* ad = A + (size_t)d * HID;
    float acc0 = ad[t] * dd * dd;
    float acc1 = ad[t + 32] * dd * dd;
    float acc2 = ad[t + 64] * dd * dd;
    int j = beg;
    for (; j + 1 < end; j += 2) {
        int s0 = ssrc[j], s1 = ssrc[j + 1];
        float w0 = dis[s0] * dd, w1 = dis[s1] * dd;
        const float* a0 = A + (size_t)s0 * HID;
        const float* a1 = A + (size_t)s1 * HID;
        float x0 = a0[t], x1 = a0[t + 32], x2 = a0[t + 64];
        float y0 = a1[t], y1 = a1[t + 32], y2 = a1[t + 64];
        acc0 += x0 * w0; acc1 += x1 * w0; acc2 += x2 * w0;
        acc0 += y0 * w1; acc1 += y1 * w1; acc2 += y2 * w1;
    }
    if (j < end) {
        int s0 = ssrc[j];
        float w0 = dis[s0] * dd;
        const float* a0 = A + (size_t)s0 * HID;
        acc0 += a0[t] * w0; acc1 += a0[t + 32] * w0; acc2 += a0[t + 64] * w0;
    }
    float* o = out + (size_t)d * HID;
    o[t]      = fmaxf(acc0 + bias[t], 0.f);
    o[t + 32] = fmaxf(acc1 + bias[t + 32], 0.f);
    o[t + 64] = fmaxf(acc2 + bias[t + 64], 0.f);
}

// ---------------- node head ----------------
__global__ void k_node_logits(const float* __restrict__ h1, const float* __restrict__ h2,
                              const float* __restrict__ Wn, const float* __restrict__ bn,
                              float* __restrict__ out) {
    int i = blockIdx.x * blockDim.x + threadIdx.x;
    if (i >= NN) return;
    float acc = bn[0];
    const float4* a = (const float4*)&h1[(size_t)i * HID];
    const float4* b = (const float4*)&h2[(size_t)i * HID];
#pragma unroll
    for (int k = 0; k < 24; ++k) {
        float4 v = a[k];
        acc += v.x * Wn[k * 4 + 0] + v.y * Wn[k * 4 + 1] + v.z * Wn[k * 4 + 2] + v.w * Wn[k * 4 + 3];
    }
#pragma unroll
    for (int k = 0; k < 24; ++k) {
        float4 v = b[k];
        acc += v.x * Wn[96 + k * 4 + 0] + v.y * Wn[96 + k * 4 + 1] + v.z * Wn[96 + k * 4 + 2] +
               v.w * Wn[96 + k * 4 + 3];
    }
    out[i] = acc;
}

// ---------------- graph pooling + graph head ----------------
__global__ __launch_bounds__(192) void k_pool(const float* __restrict__ h1,
                                              const float* __restrict__ h2,
                                              const int* __restrict__ batch,
                                              const float* __restrict__ Wg,
                                              const float* __restrict__ bg,
                                              float* __restrict__ out) {
    int g = blockIdx.x;
    int tid = threadIdx.x;  // 0..191
    int lo = 0, hi = NN;
    while (lo < hi) { int mid = (lo + hi) >> 1; if (batch[mid] < g) lo = mid + 1; else hi = mid; }
    int start = lo;
    hi = NN;
    while (lo < hi) { int mid = (lo + hi) >> 1; if (batch[mid] < g + 1) lo = mid + 1; else hi = mid; }
    int end = lo;

    const float* hsrc = (tid < HID) ? h1 : h2;
    int f = (tid < HID) ? tid : tid - HID;
    float sum = 0.f, mx = 0.f;  // h >= 0 post-relu
    for (int n = start; n < end; ++n) {
        float v = hsrc[(size_t)n * HID + f];
        sum += v;
        mx = fmaxf(mx, v);
    }
    float cnt = (float)(end - start);
    float mean = sum / fmaxf(cnt, 1.0f);
    float contrib = mean * Wg[tid] + mx * Wg[192 + tid];

    __shared__ float red[256];
    red[tid] = contrib;
    if (tid < 64) red[192 + tid] = 0.f;
    __syncthreads();
    for (int s = 128; s > 0; s >>= 1) {
        if (tid < s) red[tid] += red[tid + s];
        __syncthreads();
    }
    if (tid == 0) out[g] = red[0] + bg[0];
}

extern "C" void kernel_launch(void* const* d_in, const int* in_sizes, int n_in,
                              void* d_out, int out_size, void* d_ws, size_t ws_size,
                              hipStream_t stream) {
    const float* x    = (const float*)d_in[0];
    const int*   ei   = (const int*)d_in[1];
    const int*   srcp = ei;
    const int*   dstp = ei + NE;
    const int*   batch = (const int*)d_in[2];
    const float* W1 = (const float*)d_in[3];
    const float* b1 = (const float*)d_in[4];
    const float* W2 = (const float*)d_in[5];
    const float* b2 = (const float*)d_in[6];
    const float* Wn = (const float*)d_in[7];
    const float* bn = (const float*)d_in[8];
    const float* Wg = (const float*)d_in[9];
    const float* bg = (const float*)d_in[10];
    float* out = (float*)d_out;

    float* ws   = (float*)d_ws;
    float* dis  = ws;                            // N floats
    int*   off  = (int*)(dis + NN);              // N+1 ints
    int*   cur  = off + NN + 1;                  // N ints
    int*   ssrc = cur + NN;                      // E ints
    float* A    = (float*)(ssrc + NE);           // N*HID (hw buffer, both convs)
    float* H1   = A + (size_t)NN * HID;          // N*HID
    float* H2   = H1 + (size_t)NN * HID;         // N*HID

    const int TPB = 256;
    // CSR build
    k_zero<<<(NN + TPB) / TPB, TPB, 0, stream>>>(off, cur);
    k_hist<<<(NE + TPB - 1) / TPB, TPB, 0, stream>>>(dstp, off);
    k_scan<<<1, 1024, 0, stream>>>(off, NN + 1);
    k_dis<<<(NN + TPB - 1) / TPB, TPB, 0, stream>>>(off, dis);
    k_reorder<<<(NE + TPB - 1) / TPB, TPB, 0, stream>>>(srcp, dstp, off, cur, ssrc);

    const int aggThreads = NN * 32;

    // conv1: A = x@W1 ; H1 = relu(agg(A) + b1)
    k_gemm<INC><<<(NN + 31) / 32, 256, 0, stream>>>(x, W1, A, NN);
    k_agg<<<(aggThreads + TPB - 1) / TPB, TPB, 0, stream>>>(A, ssrc, off, dis, b1, H1);

    // conv2: A = H1@W2 ; H2 = relu(agg(A) + b2)
    k_gemm<HID><<<(NN + 31) / 32, 256, 0, stream>>>(H1, W2, A, NN);
    k_agg<<<(aggThreads + TPB - 1) / TPB, TPB, 0, stream>>>(A, ssrc, off, dis, b2, H2);

    // heads
    k_node_logits<<<(NN + TPB - 1) / TPB, TPB, 0, stream>>>(H1, H2, Wn, bn, out + NG);
    k_pool<<<NG, 192, 0, stream>>>(H1, H2, batch, Wg, bg, out);
}

// Round 3
// 584.463 us; speedup vs baseline: 7.7687x; 1.6343x over previous
//
#include <hip/hip_runtime.h>

#define NN 100000      // nodes
#define NE 1600000     // edges
#define INC 128        // in channels
#define HID 96         // hidden
#define NG 512         // graphs

// ---------------- CSR build: histogram, scan, reorder ----------------
__global__ void k_zero(int* __restrict__ off, int* __restrict__ cur) {
    int i = blockIdx.x * blockDim.x + threadIdx.x;
    if (i < NN + 1) off[i] = 0;
    if (i < NN) cur[i] = 0;
}

__global__ void k_hist(const int* __restrict__ dst, int* __restrict__ off) {
    int e = blockIdx.x * blockDim.x + threadIdx.x;
    if (e < NE) atomicAdd(&off[dst[e] + 1], 1);
}

// 3-phase scan: blockwise scan (1024 elems/block) -> scan block sums -> add
__global__ __launch_bounds__(256) void k_scan1(int* __restrict__ a, int* __restrict__ bsum, int n) {
    __shared__ int s[256];
    int base = blockIdx.x * 1024 + threadIdx.x * 4;
    int v0 = (base + 0 < n) ? a[base + 0] : 0;
    int v1 = (base + 1 < n) ? a[base + 1] : 0;
    int v2 = (base + 2 < n) ? a[base + 2] : 0;
    int v3 = (base + 3 < n) ? a[base + 3] : 0;
    v1 += v0; v2 += v1; v3 += v2;
    s[threadIdx.x] = v3;
    __syncthreads();
    for (int ofs = 1; ofs < 256; ofs <<= 1) {
        int t = (threadIdx.x >= ofs) ? s[threadIdx.x - ofs] : 0;
        __syncthreads();
        s[threadIdx.x] += t;
        __syncthreads();
    }
    int pre = (threadIdx.x > 0) ? s[threadIdx.x - 1] : 0;
    v0 += pre; v1 += pre; v2 += pre; v3 += pre;
    if (base + 0 < n) a[base + 0] = v0;
    if (base + 1 < n) a[base + 1] = v1;
    if (base + 2 < n) a[base + 2] = v2;
    if (base + 3 < n) a[base + 3] = v3;
    if (threadIdx.x == 255) bsum[blockIdx.x] = s[255];
}

__global__ __launch_bounds__(128) void k_scan2(int* __restrict__ bsum, int nb) {
    __shared__ int s[128];
    int v = (threadIdx.x < nb) ? bsum[threadIdx.x] : 0;
    s[threadIdx.x] = v;
    __syncthreads();
    for (int ofs = 1; ofs < 128; ofs <<= 1) {
        int t = (threadIdx.x >= ofs) ? s[threadIdx.x - ofs] : 0;
        __syncthreads();
        s[threadIdx.x] += t;
        __syncthreads();
    }
    if (threadIdx.x < nb) bsum[threadIdx.x] = s[threadIdx.x];  // inclusive
}

__global__ __launch_bounds__(256) void k_scan3(int* __restrict__ a, const int* __restrict__ bsum, int n) {
    int b = blockIdx.x;
    if (b == 0) return;
    int add = bsum[b - 1];
    int base = b * 1024 + threadIdx.x * 4;
#pragma unroll
    for (int j = 0; j < 4; ++j) {
        int idx = base + j;
        if (idx < n) a[idx] += add;
    }
}

// dis[i] = rsqrt(deg_in + selfloop)
__global__ void k_dis(const int* __restrict__ off, float* __restrict__ dis) {
    int i = blockIdx.x * blockDim.x + threadIdx.x;
    if (i < NN) dis[i] = rsqrtf((float)(off[i + 1] - off[i] + 1));
}

__global__ void k_reorder(const int* __restrict__ src, const int* __restrict__ dst,
                          const int* __restrict__ off, int* __restrict__ cur,
                          int* __restrict__ ssrc) {
    int e = blockIdx.x * blockDim.x + threadIdx.x;
    if (e >= NE) return;
    int d = dst[e];
    int p = off[d] + atomicAdd(&cur[d], 1);
    ssrc[p] = src[e];
}

// ---------------- register-tiled GEMM: Y[N,96] = X[N,K] @ W[K,96] ----------------
// BM=64 rows/block, 256 threads, thread tile 4 rows x 6 cols, K-chunks of 32.
template <int K>
__global__ __launch_bounds__(256) void k_gemm(const float* __restrict__ X,
                                              const float* __restrict__ W,
                                              float* __restrict__ Y) {
    __shared__ float xsT[32][64];   // X tile, transposed
    __shared__ float ws[32 * 96];   // W tile (rows contiguous)
    const int tid = threadIdx.x;
    const int row0 = blockIdx.x * 64;
    const int rg = tid >> 4;        // 0..15
    const int cg = tid & 15;        // 0..15
    const int r0 = rg * 4, c0 = cg * 6;
    float acc[4][6] = {};

    const int srow = tid & 63;      // staging row
    const int sq = tid >> 6;        // 0..3

    for (int k0 = 0; k0 < K; k0 += 32) {
        // stage X^T (zero-fill OOB rows)
        {
            int grow = row0 + srow;
            float4 v = make_float4(0.f, 0.f, 0.f, 0.f);
            float4 u = make_float4(0.f, 0.f, 0.f, 0.f);
            if (grow < NN) {
                v = *(const float4*)&X[(size_t)grow * K + k0 + sq * 4];
                u = *(const float4*)&X[(size_t)grow * K + k0 + (sq + 4) * 4];
            }
            xsT[sq * 4 + 0][srow] = v.x;
            xsT[sq * 4 + 1][srow] = v.y;
            xsT[sq * 4 + 2][srow] = v.z;
            xsT[sq * 4 + 3][srow] = v.w;
            xsT[(sq + 4) * 4 + 0][srow] = u.x;
            xsT[(sq + 4) * 4 + 1][srow] = u.y;
            xsT[(sq + 4) * 4 + 2][srow] = u.z;
            xsT[(sq + 4) * 4 + 3][srow] = u.w;
        }
        // stage W (rows are contiguous in global)
        {
            const float4* wsrc = (const float4*)(W + k0 * 96);
            float4* wdst = (float4*)ws;
            wdst[tid] = wsrc[tid];
            wdst[tid + 256] = wsrc[tid + 256];
            wdst[tid + 512] = wsrc[tid + 512];
        }
        __syncthreads();
#pragma unroll
        for (int kk = 0; kk < 32; ++kk) {
            float4 xv = *(const float4*)&xsT[kk][r0];
            float wv[6];
            *(float2*)&wv[0] = *(const float2*)&ws[kk * 96 + c0];
            *(float2*)&wv[2] = *(const float2*)&ws[kk * 96 + c0 + 2];
            *(float2*)&wv[4] = *(const float2*)&ws[kk * 96 + c0 + 4];
            float xr[4] = {xv.x, xv.y, xv.z, xv.w};
#pragma unroll
            for (int i = 0; i < 4; ++i)
#pragma unroll
                for (int j = 0; j < 6; ++j) acc[i][j] += xr[i] * wv[j];
        }
        __syncthreads();
    }
    // epilogue
#pragma unroll
    for (int i = 0; i < 4; ++i) {
        int grow = row0 + r0 + i;
        if (grow >= NN) break;
        float* yp = &Y[(size_t)grow * HID + c0];
        *(float2*)&yp[0] = make_float2(acc[i][0], acc[i][1]);
        *(float2*)&yp[2] = make_float2(acc[i][2], acc[i][3]);
        *(float2*)&yp[4] = make_float2(acc[i][4], acc[i][5]);
    }
}

// ---------------- fused GCN aggregation: selfloop + segmented sum + bias + relu ----------------
// 32 threads per destination node; thread t owns features {t, t+32, t+64}
__global__ __launch_bounds__(256) void k_agg(const float* __restrict__ A,
                                             const int* __restrict__ ssrc,
                                             const int* __restrict__ off,
                                             const float* __restrict__ dis,
                                             const float* __restrict__ bias,
                                             float* __restrict__ out) {
    int gid = blockIdx.x * blockDim.x + threadIdx.x;
    int d = gid >> 5;
    int t = gid & 31;
    if (d >= NN) return;
    const int beg = off[d], end = off[d + 1];
    const float dd = dis[d];
    const float* ad = A + (size_t)d * HID;
    float acc0 = ad[t] * dd * dd;
    float acc1 = ad[t + 32] * dd * dd;
    float acc2 = ad[t + 64] * dd * dd;
    int j = beg;
    for (; j + 3 < end; j += 4) {
        int s0 = ssrc[j], s1 = ssrc[j + 1], s2 = ssrc[j + 2], s3 = ssrc[j + 3];
        float w0 = dis[s0] * dd, w1 = dis[s1] * dd, w2 = dis[s2] * dd, w3 = dis[s3] * dd;
        const float* a0 = A + (size_t)s0 * HID;
        const float* a1 = A + (size_t)s1 * HID;
        const float* a2 = A + (size_t)s2 * HID;
        const float* a3 = A + (size_t)s3 * HID;
        float x0 = a0[t], x1 = a0[t + 32], x2 = a0[t + 64];
        float y0 = a1[t], y1 = a1[t + 32], y2 = a1[t + 64];
        float z0 = a2[t], z1 = a2[t + 32], z2 = a2[t + 64];
        float u0 = a3[t], u1 = a3[t + 32], u2 = a3[t + 64];
        acc0 += x0 * w0; acc1 += x1 * w0; acc2 += x2 * w0;
        acc0 += y0 * w1; acc1 += y1 * w1; acc2 += y2 * w1;
        acc0 += z0 * w2; acc1 += z1 * w2; acc2 += z2 * w2;
        acc0 += u0 * w3; acc1 += u1 * w3; acc2 += u2 * w3;
    }
    for (; j < end; ++j) {
        int s0 = ssrc[j];
        float w0 = dis[s0] * dd;
        const float* a0 = A + (size_t)s0 * HID;
        acc0 += a0[t] * w0; acc1 += a0[t + 32] * w0; acc2 += a0[t + 64] * w0;
    }
    float* o = out + (size_t)d * HID;
    o[t]      = fmaxf(acc0 + bias[t], 0.f);
    o[t + 32] = fmaxf(acc1 + bias[t + 32], 0.f);
    o[t + 64] = fmaxf(acc2 + bias[t + 64], 0.f);
}

// ---------------- node head ----------------
__global__ void k_node_logits(const float* __restrict__ h1, const float* __restrict__ h2,
                              const float* __restrict__ Wn, const float* __restrict__ bn,
                              float* __restrict__ out) {
    int i = blockIdx.x * blockDim.x + threadIdx.x;
    if (i >= NN) return;
    float acc = bn[0];
    const float4* a = (const float4*)&h1[(size_t)i * HID];
    const float4* b = (const float4*)&h2[(size_t)i * HID];
#pragma unroll
    for (int k = 0; k < 24; ++k) {
        float4 v = a[k];
        acc += v.x * Wn[k * 4 + 0] + v.y * Wn[k * 4 + 1] + v.z * Wn[k * 4 + 2] + v.w * Wn[k * 4 + 3];
    }
#pragma unroll
    for (int k = 0; k < 24; ++k) {
        float4 v = b[k];
        acc += v.x * Wn[96 + k * 4 + 0] + v.y * Wn[96 + k * 4 + 1] + v.z * Wn[96 + k * 4 + 2] +
               v.w * Wn[96 + k * 4 + 3];
    }
    out[i] = acc;
}

// ---------------- graph pooling + graph head ----------------
__global__ __launch_bounds__(192) void k_pool(const float* __restrict__ h1,
                                              const float* __restrict__ h2,
                                              const int* __restrict__ batch,
                                              const float* __restrict__ Wg,
                                              const float* __restrict__ bg,
                                              float* __restrict__ out) {
    int g = blockIdx.x;
    int tid = threadIdx.x;  // 0..191
    int lo = 0, hi = NN;
    while (lo < hi) { int mid = (lo + hi) >> 1; if (batch[mid] < g) lo = mid + 1; else hi = mid; }
    int start = lo;
    hi = NN;
    while (lo < hi) { int mid = (lo + hi) >> 1; if (batch[mid] < g + 1) lo = mid + 1; else hi = mid; }
    int end = lo;

    const float* hsrc = (tid < HID) ? h1 : h2;
    int f = (tid < HID) ? tid : tid - HID;
    float sum = 0.f, mx = 0.f;  // h >= 0 post-relu
    for (int n = start; n < end; ++n) {
        float v = hsrc[(size_t)n * HID + f];
        sum += v;
        mx = fmaxf(mx, v);
    }
    float cnt = (float)(end - start);
    float mean = sum / fmaxf(cnt, 1.0f);
    float contrib = mean * Wg[tid] + mx * Wg[192 + tid];

    __shared__ float red[256];
    red[tid] = contrib;
    if (tid < 64) red[192 + tid] = 0.f;
    __syncthreads();
    for (int s = 128; s > 0; s >>= 1) {
        if (tid < s) red[tid] += red[tid + s];
        __syncthreads();
    }
    if (tid == 0) out[g] = red[0] + bg[0];
}

extern "C" void kernel_launch(void* const* d_in, const int* in_sizes, int n_in,
                              void* d_out, int out_size, void* d_ws, size_t ws_size,
                              hipStream_t stream) {
    const float* x    = (const float*)d_in[0];
    const int*   ei   = (const int*)d_in[1];
    const int*   srcp = ei;
    const int*   dstp = ei + NE;
    const int*   batch = (const int*)d_in[2];
    const float* W1 = (const float*)d_in[3];
    const float* b1 = (const float*)d_in[4];
    const float* W2 = (const float*)d_in[5];
    const float* b2 = (const float*)d_in[6];
    const float* Wn = (const float*)d_in[7];
    const float* bn = (const float*)d_in[8];
    const float* Wg = (const float*)d_in[9];
    const float* bg = (const float*)d_in[10];
    float* out = (float*)d_out;

    float* ws_f = (float*)d_ws;
    float* dis  = ws_f;                          // N floats (400000 B)
    int*   off  = (int*)(dis + NN);              // N+4 ints (400016 B, keeps 16B align)
    int*   cur  = off + NN + 4;                  // N ints
    int*   bsum = cur + NN;                      // 128 ints
    int*   ssrc = bsum + 128;                    // E ints
    float* A    = (float*)(ssrc + NE);           // N*HID (hw buffer, both convs)
    float* H1   = A + (size_t)NN * HID;          // N*HID
    float* H2   = H1 + (size_t)NN * HID;         // N*HID

    const int TPB = 256;
    const int nScan = NN + 1;
    const int nbScan = (nScan + 1023) / 1024;    // 98

    // CSR build
    k_zero<<<(NN + TPB) / TPB, TPB, 0, stream>>>(off, cur);
    k_hist<<<(NE + TPB - 1) / TPB, TPB, 0, stream>>>(dstp, off);
    k_scan1<<<nbScan, 256, 0, stream>>>(off, bsum, nScan);
    k_scan2<<<1, 128, 0, stream>>>(bsum, nbScan);
    k_scan3<<<nbScan, 256, 0, stream>>>(off, bsum, nScan);
    k_dis<<<(NN + TPB - 1) / TPB, TPB, 0, stream>>>(off, dis);
    k_reorder<<<(NE + TPB - 1) / TPB, TPB, 0, stream>>>(srcp, dstp, off, cur, ssrc);

    const int aggThreads = NN * 32;

    // conv1: A = x@W1 ; H1 = relu(agg(A) + b1)
    k_gemm<INC><<<(NN + 63) / 64, 256, 0, stream>>>(x, W1, A);
    k_agg<<<(aggThreads + TPB - 1) / TPB, TPB, 0, stream>>>(A, ssrc, off, dis, b1, H1);

    // conv2: A = H1@W2 ; H2 = relu(agg(A) + b2)
    k_gemm<HID><<<(NN + 63) / 64, 256, 0, stream>>>(H1, W2, A);
    k_agg<<<(aggThreads + TPB - 1) / TPB, TPB, 0, stream>>>(A, ssrc, off, dis, b2, H2);

    // heads
    k_node_logits<<<(NN + TPB - 1) / TPB, TPB, 0, stream>>>(H1, H2, Wn, bn, out + NG);
    k_pool<<<NG, 192, 0, stream>>>(H1, H2, batch, Wg, bg, out);
}

// Round 4
// 436.929 us; speedup vs baseline: 10.3918x; 1.3377x over previous
//
#include <hip/hip_runtime.h>
#include <hip/hip_fp16.h>

#define NN 100000      // nodes
#define NE 1600000     // edges
#define INC 128        // in channels
#define HID 96         // hidden
#define NG 512         // graphs

// ---------------- CSR build: histogram, scan, reorder ----------------
__global__ void k_zero(int* __restrict__ off, int* __restrict__ cur) {
    int i = blockIdx.x * blockDim.x + threadIdx.x;
    if (i < NN + 1) off[i] = 0;
    if (i < NN) cur[i] = 0;
}

__global__ void k_hist(const int* __restrict__ dst, int* __restrict__ off) {
    int e = blockIdx.x * blockDim.x + threadIdx.x;
    if (e < NE) atomicAdd(&off[dst[e] + 1], 1);
}

// 3-phase scan: blockwise scan (1024 elems/block) -> scan block sums -> add
__global__ __launch_bounds__(256) void k_scan1(int* __restrict__ a, int* __restrict__ bsum, int n) {
    __shared__ int s[256];
    int base = blockIdx.x * 1024 + threadIdx.x * 4;
    int v0 = (base + 0 < n) ? a[base + 0] : 0;
    int v1 = (base + 1 < n) ? a[base + 1] : 0;
    int v2 = (base + 2 < n) ? a[base + 2] : 0;
    int v3 = (base + 3 < n) ? a[base + 3] : 0;
    v1 += v0; v2 += v1; v3 += v2;
    s[threadIdx.x] = v3;
    __syncthreads();
    for (int ofs = 1; ofs < 256; ofs <<= 1) {
        int t = (threadIdx.x >= ofs) ? s[threadIdx.x - ofs] : 0;
        __syncthreads();
        s[threadIdx.x] += t;
        __syncthreads();
    }
    int pre = (threadIdx.x > 0) ? s[threadIdx.x - 1] : 0;
    v0 += pre; v1 += pre; v2 += pre; v3 += pre;
    if (base + 0 < n) a[base + 0] = v0;
    if (base + 1 < n) a[base + 1] = v1;
    if (base + 2 < n) a[base + 2] = v2;
    if (base + 3 < n) a[base + 3] = v3;
    if (threadIdx.x == 255) bsum[blockIdx.x] = s[255];
}

__global__ __launch_bounds__(128) void k_scan2(int* __restrict__ bsum, int nb) {
    __shared__ int s[128];
    int v = (threadIdx.x < nb) ? bsum[threadIdx.x] : 0;
    s[threadIdx.x] = v;
    __syncthreads();
    for (int ofs = 1; ofs < 128; ofs <<= 1) {
        int t = (threadIdx.x >= ofs) ? s[threadIdx.x - ofs] : 0;
        __syncthreads();
        s[threadIdx.x] += t;
        __syncthreads();
    }
    if (threadIdx.x < nb) bsum[threadIdx.x] = s[threadIdx.x];  // inclusive
}

__global__ __launch_bounds__(256) void k_scan3(int* __restrict__ a, const int* __restrict__ bsum, int n) {
    int b = blockIdx.x;
    if (b == 0) return;
    int add = bsum[b - 1];
    int base = b * 1024 + threadIdx.x * 4;
#pragma unroll
    for (int j = 0; j < 4; ++j) {
        int idx = base + j;
        if (idx < n) a[idx] += add;
    }
}

// dis[i] = rsqrt(deg_in + selfloop)
__global__ void k_dis(const int* __restrict__ off, float* __restrict__ dis) {
    int i = blockIdx.x * blockDim.x + threadIdx.x;
    if (i < NN) dis[i] = rsqrtf((float)(off[i + 1] - off[i] + 1));
}

// scatter src into CSR order, packed with precomputed edge weight dis[s]*dis[d]
__global__ void k_reorder(const int* __restrict__ src, const int* __restrict__ dst,
                          const int* __restrict__ off, int* __restrict__ cur,
                          const float* __restrict__ dis, int2* __restrict__ ssrcw) {
    int e = blockIdx.x * blockDim.x + threadIdx.x;
    if (e >= NE) return;
    int s = src[e], d = dst[e];
    int p = off[d] + atomicAdd(&cur[d], 1);
    float w = dis[s] * dis[d];
    ssrcw[p] = make_int2(s, __float_as_int(w));
}

// ---------------- register-tiled GEMM: Yh[N,96] (fp16) = X[N,K] @ W[K,96] ----------------
// BM=64 rows/block, 256 threads, thread tile 4 rows x 6 cols, K-chunks of 32.
template <int K>
__global__ __launch_bounds__(256) void k_gemm(const float* __restrict__ X,
                                              const float* __restrict__ W,
                                              __half* __restrict__ Yh) {
    __shared__ float xsT[32][64];   // X tile, transposed
    __shared__ float ws[32 * 96];   // W tile (rows contiguous)
    const int tid = threadIdx.x;
    const int row0 = blockIdx.x * 64;
    const int rg = tid >> 4;        // 0..15
    const int cg = tid & 15;        // 0..15
    const int r0 = rg * 4, c0 = cg * 6;
    float acc[4][6] = {};

    const int srow = tid & 63;      // staging row
    const int sq = tid >> 6;        // 0..3

    for (int k0 = 0; k0 < K; k0 += 32) {
        // stage X^T (zero-fill OOB rows)
        {
            int grow = row0 + srow;
            float4 v = make_float4(0.f, 0.f, 0.f, 0.f);
            float4 u = make_float4(0.f, 0.f, 0.f, 0.f);
            if (grow < NN) {
                v = *(const float4*)&X[(size_t)grow * K + k0 + sq * 4];
                u = *(const float4*)&X[(size_t)grow * K + k0 + (sq + 4) * 4];
            }
            xsT[sq * 4 + 0][srow] = v.x;
            xsT[sq * 4 + 1][srow] = v.y;
            xsT[sq * 4 + 2][srow] = v.z;
            xsT[sq * 4 + 3][srow] = v.w;
            xsT[(sq + 4) * 4 + 0][srow] = u.x;
            xsT[(sq + 4) * 4 + 1][srow] = u.y;
            xsT[(sq + 4) * 4 + 2][srow] = u.z;
            xsT[(sq + 4) * 4 + 3][srow] = u.w;
        }
        // stage W (rows are contiguous in global)
        {
            const float4* wsrc = (const float4*)(W + k0 * 96);
            float4* wdst = (float4*)ws;
            wdst[tid] = wsrc[tid];
            wdst[tid + 256] = wsrc[tid + 256];
            wdst[tid + 512] = wsrc[tid + 512];
        }
        __syncthreads();
#pragma unroll
        for (int kk = 0; kk < 32; ++kk) {
            float4 xv = *(const float4*)&xsT[kk][r0];
            float wv[6];
            *(float2*)&wv[0] = *(const float2*)&ws[kk * 96 + c0];
            *(float2*)&wv[2] = *(const float2*)&ws[kk * 96 + c0 + 2];
            *(float2*)&wv[4] = *(const float2*)&ws[kk * 96 + c0 + 4];
            float xr[4] = {xv.x, xv.y, xv.z, xv.w};
#pragma unroll
            for (int i = 0; i < 4; ++i)
#pragma unroll
                for (int j = 0; j < 6; ++j) acc[i][j] += xr[i] * wv[j];
        }
        __syncthreads();
    }
    // epilogue: fp16 output
#pragma unroll
    for (int i = 0; i < 4; ++i) {
        int grow = row0 + r0 + i;
        if (grow >= NN) break;
        __half2* yp = (__half2*)&Yh[(size_t)grow * HID + c0];
        yp[0] = __floats2half2_rn(acc[i][0], acc[i][1]);
        yp[1] = __floats2half2_rn(acc[i][2], acc[i][3]);
        yp[2] = __floats2half2_rn(acc[i][4], acc[i][5]);
    }
}

// ---------------- fused GCN aggregation: selfloop + segmented sum + bias + relu ----------------
// 32 threads per destination node; thread t owns features {t, t+32, t+64}
__global__ __launch_bounds__(256) void k_agg(const __half* __restrict__ Ah,
                                             const int2* __restrict__ ssrcw,
                                             const int* __restrict__ off,
                                             const float* __restrict__ dis,
                                             const float* __restrict__ bias,
                                             float* __restrict__ out) {
    int gid = blockIdx.x * blockDim.x + threadIdx.x;
    int d = gid >> 5;
    int t = gid & 31;
    if (d >= NN) return;
    const int beg = off[d], end = off[d + 1];
    const float dd = dis[d];
    const __half* ad = Ah + (size_t)d * HID;
    float acc0 = __half2float(ad[t]) * dd * dd;
    float acc1 = __half2float(ad[t + 32]) * dd * dd;
    float acc2 = __half2float(ad[t + 64]) * dd * dd;
    int j = beg;
    for (; j + 3 < end; j += 4) {
        int2 e0 = ssrcw[j], e1 = ssrcw[j + 1], e2 = ssrcw[j + 2], e3 = ssrcw[j + 3];
        float w0 = __int_as_float(e0.y), w1 = __int_as_float(e1.y);
        float w2 = __int_as_float(e2.y), w3 = __int_as_float(e3.y);
        const __half* a0 = Ah + (size_t)e0.x * HID;
        const __half* a1 = Ah + (size_t)e1.x * HID;
        const __half* a2 = Ah + (size_t)e2.x * HID;
        const __half* a3 = Ah + (size_t)e3.x * HID;
        float x0 = __half2float(a0[t]), x1 = __half2float(a0[t + 32]), x2 = __half2float(a0[t + 64]);
        float y0 = __half2float(a1[t]), y1 = __half2float(a1[t + 32]), y2 = __half2float(a1[t + 64]);
        float z0 = __half2float(a2[t]), z1 = __half2float(a2[t + 32]), z2 = __half2float(a2[t + 64]);
        float u0 = __half2float(a3[t]), u1 = __half2float(a3[t + 32]), u2 = __half2float(a3[t + 64]);
        acc0 += x0 * w0; acc1 += x1 * w0; acc2 += x2 * w0;
        acc0 += y0 * w1; acc1 += y1 * w1; acc2 += y2 * w1;
        acc0 += z0 * w2; acc1 += z1 * w2; acc2 += z2 * w2;
        acc0 += u0 * w3; acc1 += u1 * w3; acc2 += u2 * w3;
    }
    for (; j < end; ++j) {
        int2 e0 = ssrcw[j];
        float w0 = __int_as_float(e0.y);
        const __half* a0 = Ah + (size_t)e0.x * HID;
        acc0 += __half2float(a0[t]) * w0;
        acc1 += __half2float(a0[t + 32]) * w0;
        acc2 += __half2float(a0[t + 64]) * w0;
    }
    float* o = out + (size_t)d * HID;
    o[t]      = fmaxf(acc0 + bias[t], 0.f);
    o[t + 32] = fmaxf(acc1 + bias[t + 32], 0.f);
    o[t + 64] = fmaxf(acc2 + bias[t + 64], 0.f);
}

// ---------------- node head ----------------
__global__ void k_node_logits(const float* __restrict__ h1, const float* __restrict__ h2,
                              const float* __restrict__ Wn, const float* __restrict__ bn,
                              float* __restrict__ out) {
    int i = blockIdx.x * blockDim.x + threadIdx.x;
    if (i >= NN) return;
    float acc = bn[0];
    const float4* a = (const float4*)&h1[(size_t)i * HID];
    const float4* b = (const float4*)&h2[(size_t)i * HID];
#pragma unroll
    for (int k = 0; k < 24; ++k) {
        float4 v = a[k];
        acc += v.x * Wn[k * 4 + 0] + v.y * Wn[k * 4 + 1] + v.z * Wn[k * 4 + 2] + v.w * Wn[k * 4 + 3];
    }
#pragma unroll
    for (int k = 0; k < 24; ++k) {
        float4 v = b[k];
        acc += v.x * Wn[96 + k * 4 + 0] + v.y * Wn[96 + k * 4 + 1] + v.z * Wn[96 + k * 4 + 2] +
               v.w * Wn[96 + k * 4 + 3];
    }
    out[i] = acc;
}

// ---------------- graph pooling + graph head ----------------
__global__ __launch_bounds__(192) void k_pool(const float* __restrict__ h1,
                                              const float* __restrict__ h2,
                                              const int* __restrict__ batch,
                                              const float* __restrict__ Wg,
                                              const float* __restrict__ bg,
                                              float* __restrict__ out) {
    int g = blockIdx.x;
    int tid = threadIdx.x;  // 0..191
    int lo = 0, hi = NN;
    while (lo < hi) { int mid = (lo + hi) >> 1; if (batch[mid] < g) lo = mid + 1; else hi = mid; }
    int start = lo;
    hi = NN;
    while (lo < hi) { int mid = (lo + hi) >> 1; if (batch[mid] < g + 1) lo = mid + 1; else hi = mid; }
    int end = lo;

    const float* hsrc = (tid < HID) ? h1 : h2;
    int f = (tid < HID) ? tid : tid - HID;
    float sum = 0.f, mx = 0.f;  // h >= 0 post-relu
    for (int n = start; n < end; ++n) {
        float v = hsrc[(size_t)n * HID + f];
        sum += v;
        mx = fmaxf(mx, v);
    }
    float cnt = (float)(end - start);
    float mean = sum / fmaxf(cnt, 1.0f);
    float contrib = mean * Wg[tid] + mx * Wg[192 + tid];

    __shared__ float red[256];
    red[tid] = contrib;
    if (tid < 64) red[192 + tid] = 0.f;
    __syncthreads();
    for (int s = 128; s > 0; s >>= 1) {
        if (tid < s) red[tid] += red[tid + s];
        __syncthreads();
    }
    if (tid == 0) out[g] = red[0] + bg[0];
}

extern "C" void kernel_launch(void* const* d_in, const int* in_sizes, int n_in,
                              void* d_out, int out_size, void* d_ws, size_t ws_size,
                              hipStream_t stream) {
    const float* x    = (const float*)d_in[0];
    const int*   ei   = (const int*)d_in[1];
    const int*   srcp = ei;
    const int*   dstp = ei + NE;
    const int*   batch = (const int*)d_in[2];
    const float* W1 = (const float*)d_in[3];
    const float* b1 = (const float*)d_in[4];
    const float* W2 = (const float*)d_in[5];
    const float* b2 = (const float*)d_in[6];
    const float* Wn = (const float*)d_in[7];
    const float* bn = (const float*)d_in[8];
    const float* Wg = (const float*)d_in[9];
    const float* bg = (const float*)d_in[10];
    float* out = (float*)d_out;

    // workspace layout (aligned to 256B per buffer)
    char* p = (char*)d_ws;
    auto alloc = [&](size_t bytes) {
        char* r = p;
        p += (bytes + 255) & ~(size_t)255;
        return (void*)r;
    };
    float* dis   = (float*)alloc(NN * 4);
    int*   off   = (int*)alloc((NN + 1) * 4);
    int*   cur   = (int*)alloc(NN * 4);
    int*   bsum  = (int*)alloc(128 * 4);
    int2*  ssrcw = (int2*)alloc((size_t)NE * 8);
    __half* Ah   = (__half*)alloc((size_t)NN * HID * 2);
    float* H1    = (float*)alloc((size_t)NN * HID * 4);
    float* H2    = (float*)alloc((size_t)NN * HID * 4);

    const int TPB = 256;
    const int nScan = NN + 1;
    const int nbScan = (nScan + 1023) / 1024;    // 98

    // CSR build
    k_zero<<<(NN + TPB) / TPB, TPB, 0, stream>>>(off, cur);
    k_hist<<<(NE + TPB - 1) / TPB, TPB, 0, stream>>>(dstp, off);
    k_scan1<<<nbScan, 256, 0, stream>>>(off, bsum, nScan);
    k_scan2<<<1, 128, 0, stream>>>(bsum, nbScan);
    k_scan3<<<nbScan, 256, 0, stream>>>(off, bsum, nScan);
    k_dis<<<(NN + TPB - 1) / TPB, TPB, 0, stream>>>(off, dis);
    k_reorder<<<(NE + TPB - 1) / TPB, TPB, 0, stream>>>(srcp, dstp, off, cur, dis, ssrcw);

    const int aggThreads = NN * 32;

    // conv1: Ah = fp16(x@W1) ; H1 = relu(agg(Ah) + b1)
    k_gemm<INC><<<(NN + 63) / 64, 256, 0, stream>>>(x, W1, Ah);
    k_agg<<<(aggThreads + TPB - 1) / TPB, TPB, 0, stream>>>(Ah, ssrcw, off, dis, b1, H1);

    // conv2: Ah = fp16(H1@W2) ; H2 = relu(agg(Ah) + b2)
    k_gemm<HID><<<(NN + 63) / 64, 256, 0, stream>>>(H1, W2, Ah);
    k_agg<<<(aggThreads + TPB - 1) / TPB, TPB, 0, stream>>>(Ah, ssrcw, off, dis, b2, H2);

    // heads
    k_node_logits<<<(NN + TPB - 1) / TPB, TPB, 0, stream>>>(H1, H2, Wn, bn, out + NG);
    k_pool<<<NG, 192, 0, stream>>>(H1, H2, batch, Wg, bg, out);
}

// Round 5
// 373.538 us; speedup vs baseline: 12.1554x; 1.1697x over previous
//
#include <hip/hip_runtime.h>
#include <hip/hip_fp16.h>

#define NN 100000      // nodes
#define NE 1600000     // edges
#define INC 128        // in channels
#define HID 96         // hidden
#define NG 512         // graphs

// ---------------- CSR build: histogram, scan, reorder ----------------
__global__ void k_zero(int* __restrict__ off, int* __restrict__ cur) {
    int i = blockIdx.x * blockDim.x + threadIdx.x;
    if (i < NN + 1) off[i] = 0;
    if (i < NN) cur[i] = 0;
}

__global__ void k_hist(const int* __restrict__ dst, int* __restrict__ off) {
    int e = blockIdx.x * blockDim.x + threadIdx.x;
    if (e < NE) atomicAdd(&off[dst[e] + 1], 1);
}

// 3-phase scan: blockwise scan (1024 elems/block) -> scan block sums -> add
__global__ __launch_bounds__(256) void k_scan1(int* __restrict__ a, int* __restrict__ bsum, int n) {
    __shared__ int s[256];
    int base = blockIdx.x * 1024 + threadIdx.x * 4;
    int v0 = (base + 0 < n) ? a[base + 0] : 0;
    int v1 = (base + 1 < n) ? a[base + 1] : 0;
    int v2 = (base + 2 < n) ? a[base + 2] : 0;
    int v3 = (base + 3 < n) ? a[base + 3] : 0;
    v1 += v0; v2 += v1; v3 += v2;
    s[threadIdx.x] = v3;
    __syncthreads();
    for (int ofs = 1; ofs < 256; ofs <<= 1) {
        int t = (threadIdx.x >= ofs) ? s[threadIdx.x - ofs] : 0;
        __syncthreads();
        s[threadIdx.x] += t;
        __syncthreads();
    }
    int pre = (threadIdx.x > 0) ? s[threadIdx.x - 1] : 0;
    v0 += pre; v1 += pre; v2 += pre; v3 += pre;
    if (base + 0 < n) a[base + 0] = v0;
    if (base + 1 < n) a[base + 1] = v1;
    if (base + 2 < n) a[base + 2] = v2;
    if (base + 3 < n) a[base + 3] = v3;
    if (threadIdx.x == 255) bsum[blockIdx.x] = s[255];
}

__global__ __launch_bounds__(128) void k_scan2(int* __restrict__ bsum, int nb) {
    __shared__ int s[128];
    int v = (threadIdx.x < nb) ? bsum[threadIdx.x] : 0;
    s[threadIdx.x] = v;
    __syncthreads();
    for (int ofs = 1; ofs < 128; ofs <<= 1) {
        int t = (threadIdx.x >= ofs) ? s[threadIdx.x - ofs] : 0;
        __syncthreads();
        s[threadIdx.x] += t;
        __syncthreads();
    }
    if (threadIdx.x < nb) bsum[threadIdx.x] = s[threadIdx.x];  // inclusive
}

__global__ __launch_bounds__(256) void k_scan3(int* __restrict__ a, const int* __restrict__ bsum, int n) {
    int b = blockIdx.x;
    if (b == 0) return;
    int add = bsum[b - 1];
    int base = b * 1024 + threadIdx.x * 4;
#pragma unroll
    for (int j = 0; j < 4; ++j) {
        int idx = base + j;
        if (idx < n) a[idx] += add;
    }
}

// dis[i] = rsqrt(deg_in + selfloop)
__global__ void k_dis(const int* __restrict__ off, float* __restrict__ dis) {
    int i = blockIdx.x * blockDim.x + threadIdx.x;
    if (i < NN) dis[i] = rsqrtf((float)(off[i + 1] - off[i] + 1));
}

// scatter src into CSR order, packed with precomputed edge weight dis[s]*dis[d]
__global__ void k_reorder(const int* __restrict__ src, const int* __restrict__ dst,
                          const int* __restrict__ off, int* __restrict__ cur,
                          const float* __restrict__ dis, int2* __restrict__ ssrcw) {
    int e = blockIdx.x * blockDim.x + threadIdx.x;
    if (e >= NE) return;
    int s = src[e], d = dst[e];
    int p = off[d] + atomicAdd(&cur[d], 1);
    float w = dis[s] * dis[d];
    ssrcw[p] = make_int2(s, __float_as_int(w));
}

// ---------------- register-tiled GEMM: Yh[N,96] (fp16) = X[N,K] @ W[K,96] ----------------
template <int K>
__global__ __launch_bounds__(256) void k_gemm(const float* __restrict__ X,
                                              const float* __restrict__ W,
                                              __half* __restrict__ Yh) {
    __shared__ float xsT[32][64];   // X tile, transposed
    __shared__ float ws[32 * 96];   // W tile (rows contiguous)
    const int tid = threadIdx.x;
    const int row0 = blockIdx.x * 64;
    const int rg = tid >> 4;        // 0..15
    const int cg = tid & 15;        // 0..15
    const int r0 = rg * 4, c0 = cg * 6;
    float acc[4][6] = {};

    const int srow = tid & 63;      // staging row
    const int sq = tid >> 6;        // 0..3

    for (int k0 = 0; k0 < K; k0 += 32) {
        {
            int grow = row0 + srow;
            float4 v = make_float4(0.f, 0.f, 0.f, 0.f);
            float4 u = make_float4(0.f, 0.f, 0.f, 0.f);
            if (grow < NN) {
                v = *(const float4*)&X[(size_t)grow * K + k0 + sq * 4];
                u = *(const float4*)&X[(size_t)grow * K + k0 + (sq + 4) * 4];
            }
            xsT[sq * 4 + 0][srow] = v.x;
            xsT[sq * 4 + 1][srow] = v.y;
            xsT[sq * 4 + 2][srow] = v.z;
            xsT[sq * 4 + 3][srow] = v.w;
            xsT[(sq + 4) * 4 + 0][srow] = u.x;
            xsT[(sq + 4) * 4 + 1][srow] = u.y;
            xsT[(sq + 4) * 4 + 2][srow] = u.z;
            xsT[(sq + 4) * 4 + 3][srow] = u.w;
        }
        {
            const float4* wsrc = (const float4*)(W + k0 * 96);
            float4* wdst = (float4*)ws;
            wdst[tid] = wsrc[tid];
            wdst[tid + 256] = wsrc[tid + 256];
            wdst[tid + 512] = wsrc[tid + 512];
        }
        __syncthreads();
#pragma unroll
        for (int kk = 0; kk < 32; ++kk) {
            float4 xv = *(const float4*)&xsT[kk][r0];
            float wv[6];
            *(float2*)&wv[0] = *(const float2*)&ws[kk * 96 + c0];
            *(float2*)&wv[2] = *(const float2*)&ws[kk * 96 + c0 + 2];
            *(float2*)&wv[4] = *(const float2*)&ws[kk * 96 + c0 + 4];
            float xr[4] = {xv.x, xv.y, xv.z, xv.w};
#pragma unroll
            for (int i = 0; i < 4; ++i)
#pragma unroll
                for (int j = 0; j < 6; ++j) acc[i][j] += xr[i] * wv[j];
        }
        __syncthreads();
    }
#pragma unroll
    for (int i = 0; i < 4; ++i) {
        int grow = row0 + r0 + i;
        if (grow >= NN) break;
        __half2* yp = (__half2*)&Yh[(size_t)grow * HID + c0];
        yp[0] = __floats2half2_rn(acc[i][0], acc[i][1]);
        yp[1] = __floats2half2_rn(acc[i][2], acc[i][3]);
        yp[2] = __floats2half2_rn(acc[i][4], acc[i][5]);
    }
}

// ---------------- fused GCN aggregation + node-logit partial ----------------
// 32 threads per destination node; thread t owns features {t, t+32, t+64}.
// PHASE 1: nodeOut[d] = bn + h1 . Wn[0:96]      (h1 written to out)
// PHASE 2: nodeOut[d] += h2 . Wn[96:192]        (h2 written to out)
template <int PHASE>
__global__ __launch_bounds__(256) void k_agg(const __half* __restrict__ Ah,
                                             const int2* __restrict__ ssrcw,
                                             const int* __restrict__ off,
                                             const float* __restrict__ dis,
                                             const float* __restrict__ bias,
                                             const float* __restrict__ Wn,
                                             const float* __restrict__ bn,
                                             float* __restrict__ out,
                                             float* __restrict__ nodeOut) {
    int gid = blockIdx.x * blockDim.x + threadIdx.x;
    int d = gid >> 5;
    int t = gid & 31;
    if (d >= NN) return;
    const int beg = off[d], end = off[d + 1];
    const float dd = dis[d];
    const __half* ad = Ah + (size_t)d * HID;
    float acc0 = __half2float(ad[t]) * dd * dd;
    float acc1 = __half2float(ad[t + 32]) * dd * dd;
    float acc2 = __half2float(ad[t + 64]) * dd * dd;
    int j = beg;
    for (; j + 3 < end; j += 4) {
        int2 e0 = ssrcw[j], e1 = ssrcw[j + 1], e2 = ssrcw[j + 2], e3 = ssrcw[j + 3];
        float w0 = __int_as_float(e0.y), w1 = __int_as_float(e1.y);
        float w2 = __int_as_float(e2.y), w3 = __int_as_float(e3.y);
        const __half* a0 = Ah + (size_t)e0.x * HID;
        const __half* a1 = Ah + (size_t)e1.x * HID;
        const __half* a2 = Ah + (size_t)e2.x * HID;
        const __half* a3 = Ah + (size_t)e3.x * HID;
        float x0 = __half2float(a0[t]), x1 = __half2float(a0[t + 32]), x2 = __half2float(a0[t + 64]);
        float y0 = __half2float(a1[t]), y1 = __half2float(a1[t + 32]), y2 = __half2float(a1[t + 64]);
        float z0 = __half2float(a2[t]), z1 = __half2float(a2[t + 32]), z2 = __half2float(a2[t + 64]);
        float u0 = __half2float(a3[t]), u1 = __half2float(a3[t + 32]), u2 = __half2float(a3[t + 64]);
        acc0 += x0 * w0; acc1 += x1 * w0; acc2 += x2 * w0;
        acc0 += y0 * w1; acc1 += y1 * w1; acc2 += y2 * w1;
        acc0 += z0 * w2; acc1 += z1 * w2; acc2 += z2 * w2;
        acc0 += u0 * w3; acc1 += u1 * w3; acc2 += u2 * w3;
    }
    for (; j < end; ++j) {
        int2 e0 = ssrcw[j];
        float w0 = __int_as_float(e0.y);
        const __half* a0 = Ah + (size_t)e0.x * HID;
        acc0 += __half2float(a0[t]) * w0;
        acc1 += __half2float(a0[t + 32]) * w0;
        acc2 += __half2float(a0[t + 64]) * w0;
    }
    float h0 = fmaxf(acc0 + bias[t], 0.f);
    float h1v = fmaxf(acc1 + bias[t + 32], 0.f);
    float h2v = fmaxf(acc2 + bias[t + 64], 0.f);
    float* o = out + (size_t)d * HID;
    o[t] = h0; o[t + 32] = h1v; o[t + 64] = h2v;

    // node-logit partial: dot with Wn slice, reduce over the 32-lane group
    const int woff = (PHASE == 1) ? 0 : 96;
    float partial = h0 * Wn[woff + t] + h1v * Wn[woff + t + 32] + h2v * Wn[woff + t + 64];
#pragma unroll
    for (int m = 16; m; m >>= 1) partial += __shfl_down(partial, m, 32);
    if (t == 0) {
        if (PHASE == 1) nodeOut[d] = partial + bn[0];
        else            nodeOut[d] += partial;
    }
}

// ---------------- graph pooling + graph head ----------------
// 768 threads: 4 node-ways x 192 features
__global__ __launch_bounds__(768) void k_pool(const float* __restrict__ h1,
                                              const float* __restrict__ h2,
                                              const int* __restrict__ batch,
                                              const float* __restrict__ Wg,
                                              const float* __restrict__ bg,
                                              float* __restrict__ out) {
    int g = blockIdx.x;
    int tid = threadIdx.x;       // 0..767
    int way = tid / 192;         // 0..3
    int f = tid - way * 192;     // 0..191

    int lo = 0, hi = NN;
    while (lo < hi) { int mid = (lo + hi) >> 1; if (batch[mid] < g) lo = mid + 1; else hi = mid; }
    int start = lo;
    hi = NN;
    while (lo < hi) { int mid = (lo + hi) >> 1; if (batch[mid] < g + 1) lo = mid + 1; else hi = mid; }
    int end = lo;

    const float* hsrc = (f < HID) ? h1 : h2;
    int ff = (f < HID) ? f : f - HID;
    float sum = 0.f, mx = 0.f;  // h >= 0 post-relu
    for (int n = start + way; n < end; n += 4) {
        float v = hsrc[(size_t)n * HID + ff];
        sum += v;
        mx = fmaxf(mx, v);
    }
    __shared__ float rsum[4][192];
    __shared__ float rmax[4][192];
    rsum[way][f] = sum;
    rmax[way][f] = mx;
    __syncthreads();
    if (way == 0) {
        sum = rsum[0][f] + rsum[1][f] + rsum[2][f] + rsum[3][f];
        mx = fmaxf(fmaxf(rmax[0][f], rmax[1][f]), fmaxf(rmax[2][f], rmax[3][f]));
        float cnt = (float)(end - start);
        float mean = sum / fmaxf(cnt, 1.0f);
        rsum[0][f] = mean * Wg[f] + mx * Wg[192 + f];
    }
    __syncthreads();
    if (tid < 64) {
        float acc = rsum[0][tid] + rsum[0][tid + 64] + rsum[0][tid + 128];
#pragma unroll
        for (int m = 32; m; m >>= 1) acc += __shfl_down(acc, m, 64);
        if (tid == 0) out[g] = acc + bg[0];
    }
}

extern "C" void kernel_launch(void* const* d_in, const int* in_sizes, int n_in,
                              void* d_out, int out_size, void* d_ws, size_t ws_size,
                              hipStream_t stream) {
    const float* x    = (const float*)d_in[0];
    const int*   ei   = (const int*)d_in[1];
    const int*   srcp = ei;
    const int*   dstp = ei + NE;
    const int*   batch = (const int*)d_in[2];
    const float* W1 = (const float*)d_in[3];
    const float* b1 = (const float*)d_in[4];
    const float* W2 = (const float*)d_in[5];
    const float* b2 = (const float*)d_in[6];
    const float* Wn = (const float*)d_in[7];
    const float* bn = (const float*)d_in[8];
    const float* Wg = (const float*)d_in[9];
    const float* bg = (const float*)d_in[10];
    float* out = (float*)d_out;

    char* p = (char*)d_ws;
    auto alloc = [&](size_t bytes) {
        char* r = p;
        p += (bytes + 255) & ~(size_t)255;
        return (void*)r;
    };
    float* dis   = (float*)alloc(NN * 4);
    int*   off   = (int*)alloc((NN + 1) * 4);
    int*   cur   = (int*)alloc(NN * 4);
    int*   bsum  = (int*)alloc(128 * 4);
    int2*  ssrcw = (int2*)alloc((size_t)NE * 8);
    __half* Ah   = (__half*)alloc((size_t)NN * HID * 2);
    float* H1    = (float*)alloc((size_t)NN * HID * 4);
    float* H2    = (float*)alloc((size_t)NN * HID * 4);

    const int TPB = 256;
    const int nScan = NN + 1;
    const int nbScan = (nScan + 1023) / 1024;    // 98

    // CSR build
    k_zero<<<(NN + TPB) / TPB, TPB, 0, stream>>>(off, cur);
    k_hist<<<(NE + TPB - 1) / TPB, TPB, 0, stream>>>(dstp, off);
    k_scan1<<<nbScan, 256, 0, stream>>>(off, bsum, nScan);
    k_scan2<<<1, 128, 0, stream>>>(bsum, nbScan);
    k_scan3<<<nbScan, 256, 0, stream>>>(off, bsum, nScan);
    k_dis<<<(NN + TPB - 1) / TPB, TPB, 0, stream>>>(off, dis);
    k_reorder<<<(NE + TPB - 1) / TPB, TPB, 0, stream>>>(srcp, dstp, off, cur, dis, ssrcw);

    const int aggThreads = NN * 32;
    float* nodeOut = out + NG;

    // conv1: Ah = fp16(x@W1) ; H1 = relu(agg(Ah) + b1) ; nodeOut = bn + H1.Wn[:96]
    k_gemm<INC><<<(NN + 63) / 64, 256, 0, stream>>>(x, W1, Ah);
    k_agg<1><<<(aggThreads + TPB - 1) / TPB, TPB, 0, stream>>>(Ah, ssrcw, off, dis, b1, Wn, bn, H1, nodeOut);

    // conv2: Ah = fp16(H1@W2) ; H2 = relu(agg(Ah) + b2) ; nodeOut += H2.Wn[96:]
    k_gemm<HID><<<(NN + 63) / 64, 256, 0, stream>>>(H1, W2, Ah);
    k_agg<2><<<(aggThreads + TPB - 1) / TPB, TPB, 0, stream>>>(Ah, ssrcw, off, dis, b2, Wn, bn, H2, nodeOut);

    // pooling + graph head
    k_pool<<<NG, 768, 0, stream>>>(H1, H2, batch, Wg, bg, out);
}